// Round 5
// baseline (56.692 us; speedup 1.0000x reference)
//
#include <hip/hip_runtime.h>

// RoiAlign on FPN pyramid.  Output: (1, N, 14, 14, 256) fp32.  N = 512.
// R4: two-phase. Setup kernel precomputes per-(box,position) sampling records
//     (offsets/weights/level) into d_ws; main kernel is a lean gather+lerp
//     stream (record broadcast -> 4 float4 loads -> lerp -> nt store).
//     Keeps XCD-aware box-chunk swizzle + nontemporal stores + PPW=2.
//     Fallback monolithic kernel if ws_size is too small.

#define CROP 14
#define POS (CROP * CROP)        // 196
#define C 256
#define CANON 224.0f
#define EPSF 1e-7f

typedef float vfloat4 __attribute__((ext_vector_type(4)));

struct __align__(16) Rec {
    int   off[4];   // element offsets of TL,TR,BL,BR within selected level
    float fx, fy;
    int   meta;     // level | (valid << 3)
    int   pad;
};

// ---------------- setup: one thread per (box, position) ----------------
__global__ __launch_bounds__(256) void setup_kernel(
    const int* __restrict__ image_shape,
    const float* __restrict__ boxes,
    Rec* __restrict__ recs,
    int total)
{
    const int idx = blockIdx.x * 256 + threadIdx.x;
    if (idx >= total) return;
    const int box = idx / POS;
    const int p   = idx % POS;
    const int py  = p / CROP;
    const int px  = p % CROP;

    const float imgh = (float)image_shape[1];
    const float imgw = (float)image_shape[2];

    const float bx1 = boxes[box * 4 + 0];
    const float by1 = boxes[box * 4 + 1];
    const float bx2 = boxes[box * 4 + 2];
    const float by2 = boxes[box * 4 + 3];

    const float w  = bx2 - bx1;
    const float h  = by2 - by1;
    const float sz = sqrtf(w * h);
    float lvf = floorf(1.0f + log2f(sz / CANON + EPSF));
    lvf = fminf(fmaxf(lvf, 0.0f), 4.0f);
    const int lv = (int)lvf;

    const int   s  = 256 >> lv;
    const float fh = (float)s;
    const float fw = (float)s;

    const float ny1 = by1 / imgh * fh / (fh - 1.0f);
    const float nx1 = bx1 / imgw * fw / (fw - 1.0f);
    const float ny2 = (by2 / imgh * fh - 1.0f) / (fh - 1.0f);
    const float nx2 = (bx2 / imgw * fw - 1.0f) / (fw - 1.0f);

    const float ty = (float)py / (float)(CROP - 1);
    const float tx = (float)px / (float)(CROP - 1);
    const float yc = (ny1 * (1.0f - ty) + ny2 * ty) * (fh - 1.0f);
    const float xc = (nx1 * (1.0f - tx) + nx2 * tx) * (fw - 1.0f);

    const float ylo = floorf(yc);
    const float fy  = yc - ylo;
    const int y0  = (int)fminf(fmaxf(ylo,        0.0f), fh - 1.0f);
    const int y1i = (int)fminf(fmaxf(ylo + 1.0f, 0.0f), fh - 1.0f);
    const bool vy = (yc >= 0.0f) && (yc <= fh - 1.0f);

    const float xlo = floorf(xc);
    const float fx  = xc - xlo;
    const int x0  = (int)fminf(fmaxf(xlo,        0.0f), fw - 1.0f);
    const int x1i = (int)fminf(fmaxf(xlo + 1.0f, 0.0f), fw - 1.0f);
    const bool vx = (xc >= 0.0f) && (xc <= fw - 1.0f);

    Rec r;
    r.off[0] = (y0  * s + x0 ) * C;
    r.off[1] = (y0  * s + x1i) * C;
    r.off[2] = (y1i * s + x0 ) * C;
    r.off[3] = (y1i * s + x1i) * C;
    r.fx = fx; r.fy = fy;
    r.meta = lv | ((vy && vx) ? 8 : 0);
    r.pad = 0;
    recs[idx] = r;
}

// ---------------- main: lean gather + lerp ----------------
__global__ __launch_bounds__(256) void roi_gather_kernel(
    const Rec* __restrict__ recs,
    const float* __restrict__ f0,
    const float* __restrict__ f1,
    const float* __restrict__ f2,
    const float* __restrict__ f3,
    const float* __restrict__ f4,
    float* __restrict__ out)
{
    // bijective XCD swizzle: keep consecutive logical blocks (same boxes) on
    // one XCD's L2.
    const int nwg = gridDim.x;
    const int q = nwg >> 3, r = nwg & 7;
    const int xcd = blockIdx.x & 7, slot = blockIdx.x >> 3;
    const int blk = (xcd < r ? xcd * (q + 1) : r * (q + 1) + (xcd - r) * q) + slot;

    const int wave = threadIdx.x >> 6;
    const int lane = threadIdx.x & 63;
    const int g0 = blk * 8 + wave * 2;   // two positions per wave
    const int cbase = lane * 4;

    #pragma unroll
    for (int k = 0; k < 2; ++k) {
        const int g = g0 + k;
        const Rec rec = recs[g];          // same addr across wave -> broadcast
        const int lv = rec.meta & 7;
        const float* __restrict__ f =
            (lv == 0) ? f0 : (lv == 1) ? f1 : (lv == 2) ? f2 : (lv == 3) ? f3 : f4;

        vfloat4 o;
        if (rec.meta & 8) {
            const vfloat4 tl = *(const vfloat4*)(f + rec.off[0] + cbase);
            const vfloat4 tr = *(const vfloat4*)(f + rec.off[1] + cbase);
            const vfloat4 bl = *(const vfloat4*)(f + rec.off[2] + cbase);
            const vfloat4 br = *(const vfloat4*)(f + rec.off[3] + cbase);
            const vfloat4 top = tl + (tr - tl) * rec.fx;
            const vfloat4 bot = bl + (br - bl) * rec.fx;
            o = top + (bot - top) * rec.fy;
        } else {
            o = (vfloat4)0.0f;
        }
        __builtin_nontemporal_store(o, (vfloat4*)(out + (size_t)g * C + cbase));
    }
}

// ---------------- fallback monolithic (R1-style + nt store) ----------------
__global__ __launch_bounds__(256) void roi_align_mono(
    const int* __restrict__ image_shape,
    const float* __restrict__ boxes,
    const float* __restrict__ f0,
    const float* __restrict__ f1,
    const float* __restrict__ f2,
    const float* __restrict__ f3,
    const float* __restrict__ f4,
    float* __restrict__ out)
{
    const int nwg = gridDim.x;
    const int q = nwg >> 3, r = nwg & 7;
    const int xcd = blockIdx.x & 7, slot = blockIdx.x >> 3;
    const int blk = (xcd < r ? xcd * (q + 1) : r * (q + 1) + (xcd - r) * q) + slot;

    const int box      = blk / 25;
    const int blkInBox = blk % 25;
    const int wave = threadIdx.x >> 6;
    const int lane = threadIdx.x & 63;
    const int p0 = blkInBox * 8 + wave * 2;

    const float imgh = (float)image_shape[1];
    const float imgw = (float)image_shape[2];
    const float bx1 = boxes[box * 4 + 0];
    const float by1 = boxes[box * 4 + 1];
    const float bx2 = boxes[box * 4 + 2];
    const float by2 = boxes[box * 4 + 3];

    const float w  = bx2 - bx1;
    const float h  = by2 - by1;
    const float sz = sqrtf(w * h);
    float lvf = floorf(1.0f + log2f(sz / CANON + EPSF));
    lvf = fminf(fmaxf(lvf, 0.0f), 4.0f);
    const int lv = (int)lvf;

    const int   s  = 256 >> lv;
    const float fh = (float)s;
    const float fw = (float)s;

    const float ny1 = by1 / imgh * fh / (fh - 1.0f);
    const float nx1 = bx1 / imgw * fw / (fw - 1.0f);
    const float ny2 = (by2 / imgh * fh - 1.0f) / (fh - 1.0f);
    const float nx2 = (bx2 / imgw * fw - 1.0f) / (fw - 1.0f);

    const float* __restrict__ f =
        (lv == 0) ? f0 : (lv == 1) ? f1 : (lv == 2) ? f2 : (lv == 3) ? f3 : f4;
    const int cbase = lane * 4;

    #pragma unroll
    for (int k = 0; k < 2; ++k) {
        const int p = p0 + k;
        if (p >= POS) continue;
        const int py = p / CROP;
        const int px = p % CROP;
        const float ty = (float)py / (float)(CROP - 1);
        const float tx = (float)px / (float)(CROP - 1);
        const float yc = (ny1 * (1.0f - ty) + ny2 * ty) * (fh - 1.0f);
        const float xc = (nx1 * (1.0f - tx) + nx2 * tx) * (fw - 1.0f);

        const float ylo = floorf(yc);
        const float fy  = yc - ylo;
        const int y0  = (int)fminf(fmaxf(ylo,        0.0f), fh - 1.0f);
        const int y1i = (int)fminf(fmaxf(ylo + 1.0f, 0.0f), fh - 1.0f);
        const bool vy = (yc >= 0.0f) && (yc <= fh - 1.0f);

        const float xlo = floorf(xc);
        const float fx  = xc - xlo;
        const int x0  = (int)fminf(fmaxf(xlo,        0.0f), fw - 1.0f);
        const int x1i = (int)fminf(fmaxf(xlo + 1.0f, 0.0f), fw - 1.0f);
        const bool vx = (xc >= 0.0f) && (xc <= fw - 1.0f);

        vfloat4 o;
        if (vy && vx) {
            const vfloat4 tl = *(const vfloat4*)(f + ((size_t)y0  * s + x0 ) * C + cbase);
            const vfloat4 tr = *(const vfloat4*)(f + ((size_t)y0  * s + x1i) * C + cbase);
            const vfloat4 bl = *(const vfloat4*)(f + ((size_t)y1i * s + x0 ) * C + cbase);
            const vfloat4 br = *(const vfloat4*)(f + ((size_t)y1i * s + x1i) * C + cbase);
            const vfloat4 top = tl + (tr - tl) * fx;
            const vfloat4 bot = bl + (br - bl) * fx;
            o = top + (bot - top) * fy;
        } else { o = (vfloat4)0.0f; }
        __builtin_nontemporal_store(
            o, (vfloat4*)(out + ((size_t)box * POS + p) * C + cbase));
    }
}

extern "C" void kernel_launch(void* const* d_in, const int* in_sizes, int n_in,
                              void* d_out, int out_size, void* d_ws, size_t ws_size,
                              hipStream_t stream) {
    const int*   image_shape = (const int*)d_in[0];
    const float* boxes       = (const float*)d_in[1];
    // d_in[2] = scores (unused by the reference output)
    const float* f0 = (const float*)d_in[3];
    const float* f1 = (const float*)d_in[4];
    const float* f2 = (const float*)d_in[5];
    const float* f3 = (const float*)d_in[6];
    const float* f4 = (const float*)d_in[7];
    float* out = (float*)d_out;

    const int N = in_sizes[1] / 4;   // boxes: (1, N, 4)
    const int total = N * POS;
    const size_t rec_bytes = (size_t)total * sizeof(Rec);

    if (ws_size >= rec_bytes && (total % 8) == 0) {
        Rec* recs = (Rec*)d_ws;
        setup_kernel<<<(total + 255) / 256, 256, 0, stream>>>(
            image_shape, boxes, recs, total);
        roi_gather_kernel<<<total / 8, 256, 0, stream>>>(
            recs, f0, f1, f2, f3, f4, out);
    } else {
        roi_align_mono<<<N * 25, 256, 0, stream>>>(
            image_shape, boxes, f0, f1, f2, f3, f4, out);
    }
}

// Round 6
// 52.325 us; speedup vs baseline: 1.0835x; 1.0835x over previous
//
#include <hip/hip_runtime.h>

// RoiAlign on FPN pyramid.  Output: (1, N, 14, 14, 256) fp32.  N = 512.
// R5: single mono kernel (R1 structure, PPW=2, XCD box-chunk swizzle) with
//     inline-asm stores `global_store_dwordx4 ... sc0 sc1 nt` to bypass
//     L2/LLC allocation so the FPN pyramid stays resident in Infinity Cache
//     across graph replays (reads then come from LLC, HBM carries only the
//     write stream).

#define CROP 14
#define POS (CROP * CROP)        // 196
#define C 256
#define CANON 224.0f
#define EPSF 1e-7f

typedef float vfloat4 __attribute__((ext_vector_type(4)));

__device__ __forceinline__ void store_bypass(float* p, vfloat4 v) {
    // sc0+sc1: system-scope (no L2/LLC allocation), nt: non-temporal hint.
    asm volatile("global_store_dwordx4 %0, %1, off sc0 sc1 nt"
                 :
                 : "v"(p), "v"(v)
                 : "memory");
}

__global__ __launch_bounds__(256) void roi_align_kernel(
    const int* __restrict__ image_shape,
    const float* __restrict__ boxes,
    const float* __restrict__ f0,
    const float* __restrict__ f1,
    const float* __restrict__ f2,
    const float* __restrict__ f3,
    const float* __restrict__ f4,
    float* __restrict__ out)
{
    // bijective XCD swizzle: consecutive logical blocks (same box) -> one XCD.
    const int nwg = gridDim.x;
    const int q = nwg >> 3, r = nwg & 7;
    const int xcd = blockIdx.x & 7, slot = blockIdx.x >> 3;
    const int blk = (xcd < r ? xcd * (q + 1) : r * (q + 1) + (xcd - r) * q) + slot;

    const int box      = blk / 25;
    const int blkInBox = blk % 25;
    const int wave = threadIdx.x >> 6;
    const int lane = threadIdx.x & 63;
    const int p0 = blkInBox * 8 + wave * 2;

    const float imgh = (float)image_shape[1];
    const float imgw = (float)image_shape[2];
    const float bx1 = boxes[box * 4 + 0];
    const float by1 = boxes[box * 4 + 1];
    const float bx2 = boxes[box * 4 + 2];
    const float by2 = boxes[box * 4 + 3];

    // level selection (reference semantics)
    const float w  = bx2 - bx1;
    const float h  = by2 - by1;
    const float sz = sqrtf(w * h);
    float lvf = floorf(1.0f + log2f(sz / CANON + EPSF));
    lvf = fminf(fmaxf(lvf, 0.0f), 4.0f);
    const int lv = (int)lvf;

    const int   s  = 256 >> lv;
    const float fh = (float)s;
    const float fw = (float)s;

    const float ny1 = by1 / imgh * fh / (fh - 1.0f);
    const float nx1 = bx1 / imgw * fw / (fw - 1.0f);
    const float ny2 = (by2 / imgh * fh - 1.0f) / (fh - 1.0f);
    const float nx2 = (bx2 / imgw * fw - 1.0f) / (fw - 1.0f);

    const float* __restrict__ f =
        (lv == 0) ? f0 : (lv == 1) ? f1 : (lv == 2) ? f2 : (lv == 3) ? f3 : f4;
    const int cbase = lane * 4;

    #pragma unroll
    for (int k = 0; k < 2; ++k) {
        const int p = p0 + k;
        if (p >= POS) continue;
        const int py = p / CROP;
        const int px = p % CROP;
        const float ty = (float)py / (float)(CROP - 1);
        const float tx = (float)px / (float)(CROP - 1);
        const float yc = (ny1 * (1.0f - ty) + ny2 * ty) * (fh - 1.0f);
        const float xc = (nx1 * (1.0f - tx) + nx2 * tx) * (fw - 1.0f);

        const float ylo = floorf(yc);
        const float fy  = yc - ylo;
        const int y0  = (int)fminf(fmaxf(ylo,        0.0f), fh - 1.0f);
        const int y1i = (int)fminf(fmaxf(ylo + 1.0f, 0.0f), fh - 1.0f);
        const bool vy = (yc >= 0.0f) && (yc <= fh - 1.0f);

        const float xlo = floorf(xc);
        const float fx  = xc - xlo;
        const int x0  = (int)fminf(fmaxf(xlo,        0.0f), fw - 1.0f);
        const int x1i = (int)fminf(fmaxf(xlo + 1.0f, 0.0f), fw - 1.0f);
        const bool vx = (xc >= 0.0f) && (xc <= fw - 1.0f);

        vfloat4 o;
        if (vy && vx) {
            const vfloat4 tl = *(const vfloat4*)(f + ((size_t)y0  * s + x0 ) * C + cbase);
            const vfloat4 tr = *(const vfloat4*)(f + ((size_t)y0  * s + x1i) * C + cbase);
            const vfloat4 bl = *(const vfloat4*)(f + ((size_t)y1i * s + x0 ) * C + cbase);
            const vfloat4 br = *(const vfloat4*)(f + ((size_t)y1i * s + x1i) * C + cbase);
            const vfloat4 top = tl + (tr - tl) * fx;
            const vfloat4 bot = bl + (br - bl) * fx;
            o = top + (bot - top) * fy;
        } else { o = (vfloat4)0.0f; }

        store_bypass(out + ((size_t)box * POS + p) * C + cbase, o);
    }
}

extern "C" void kernel_launch(void* const* d_in, const int* in_sizes, int n_in,
                              void* d_out, int out_size, void* d_ws, size_t ws_size,
                              hipStream_t stream) {
    const int*   image_shape = (const int*)d_in[0];
    const float* boxes       = (const float*)d_in[1];
    // d_in[2] = scores (unused by the reference output)
    const float* f0 = (const float*)d_in[3];
    const float* f1 = (const float*)d_in[4];
    const float* f2 = (const float*)d_in[5];
    const float* f3 = (const float*)d_in[6];
    const float* f4 = (const float*)d_in[7];
    float* out = (float*)d_out;

    const int N = in_sizes[1] / 4;  // boxes: (1, N, 4)

    roi_align_kernel<<<N * 25, 256, 0, stream>>>(
        image_shape, boxes, f0, f1, f2, f3, f4, out);
}